// Round 9
// baseline (156.007 us; speedup 1.0000x reference)
//
#include <hip/hip_runtime.h>

typedef unsigned short u16;
typedef short v8s __attribute__((ext_vector_type(8)));
typedef float v4f __attribute__((ext_vector_type(4)));

namespace {
constexpr int kC = 384;
constexpr int kN1 = 513;
constexpr int kH = 6;
constexpr int kBH = 48;      // B*H
constexpr int kRows = 4104;  // B*N1 tokens per half
constexpr int kRows2 = 8208; // B*M
constexpr int kPld = 576;    // Vt k-stride in bf16 elems (64*9)
}  // namespace

__device__ __forceinline__ u16 f2b(float f) {
  unsigned int u = __float_as_uint(f);
  u += 0x7fffu + ((u >> 16) & 1u);
  return (u16)(u >> 16);
}

__device__ __forceinline__ int gumbel_argmax(const float* __restrict__ w,
                                             const float* __restrict__ g) {
  float v0 = w[0] + g[0], v1 = w[1] + g[1], v2 = w[2] + g[2], v3 = w[3] + g[3];
  int j = 0;
  float m = v0;
  if (v1 > m) { m = v1; j = 1; }
  if (v2 > m) { m = v2; j = 2; }
  if (v3 > m) { m = v3; j = 3; }
  return j;
}

// Stage a 64k x 128c tile of a NATURAL-layout fp32 weight W[k][c] into LDS as
// bf16 [c][k] (MFMA B/A-operand layout). Inline transpose: 16 column-strided
// global reads per thread (4x64B segments/wave-instr, L2-resident weights);
// LDS writes are 2-way bank aliased (free). Covers c0..c0+128, k0..k0+64.
__device__ __forceinline__ void stage_wt(u16 (*dst)[72],
                                         const float* __restrict__ W, int k0,
                                         int c0, int tid) {
  const int kg = (tid & 3) * 16;
  const int cr = tid >> 2;  // 0..63
  for (int p = 0; p < 2; ++p) {
    const int c = p * 64 + cr;
    const float* src = W + (size_t)(k0 + kg) * kC + c0 + c;
    v8s t0, t1;
    for (int i = 0; i < 8; ++i) t0[i] = (short)f2b(src[(size_t)i * kC]);
    for (int i = 0; i < 8; ++i) t1[i] = (short)f2b(src[(size_t)(i + 8) * kC]);
    *(v8s*)&dst[c][kg] = t0;
    *(v8s*)&dst[c][kg + 8] = t1;
  }
}

// ---- fused QKV projections, bf16 MFMA; x AND weights converted inline ----
// 1-D grid of 400: xcd=bid&7 pairs to op=xcd>>1 (weights L2-resident per XCD
// pair). op0: Q = 0.125*(xsel @ Wq + bq); op1: K; op2/3: Vt (transposed out).
__global__ __launch_bounds__(256) void qkv_mfma(
    const float* __restrict__ x, const float* __restrict__ Wq1,
    const float* __restrict__ Wq2, const float* __restrict__ Wk1,
    const float* __restrict__ Wk2, const float* __restrict__ Wv1,
    const float* __restrict__ Wv2, const float* __restrict__ bq1,
    const float* __restrict__ bq2, const float* __restrict__ bk1,
    const float* __restrict__ bk2, const float* __restrict__ bv1,
    const float* __restrict__ bv2, const float* __restrict__ wts,
    const float* __restrict__ gum, u16* __restrict__ Qb, u16* __restrict__ Kb,
    u16* __restrict__ Vt1, u16* __restrict__ Vt2) {
  const int bid = blockIdx.x;
  const int xcd = bid & 7;
  const int op = xcd >> 1;
  const int wu = (bid >> 3) * 2 + (xcd & 1);
  if (wu >= 99) return;
  const int mb33 = wu / 3, nb3 = wu - mb33 * 3;

  __shared__ __align__(16) u16 As[128][72];
  __shared__ __align__(16) u16 Bs[128][72];
  const int j = gumbel_argmax(wts, gum);
  const bool vmode = (op >= 2);
  const float* bias;
  int xoff;
  const float* Wn;  // natural-layout selected weight
  if (op == 0) {
    bias = (j < 2) ? bq1 : bq2; xoff = (j < 2) ? 0 : kN1;
    Wn = (j < 2) ? Wq1 : Wq2;
  } else if (op == 1) {
    const bool u1 = (j == 0 || j == 2);
    bias = u1 ? bk1 : bk2; xoff = u1 ? 0 : kN1;
    Wn = u1 ? Wk1 : Wk2;
  } else if (op == 2) {
    bias = bv1; xoff = 0; Wn = Wv1;
  } else {
    bias = bv2; xoff = kN1; Wn = Wv2;
  }
  const int m0 = (vmode ? nb3 : mb33) * 128;
  const int n0 = (vmode ? mb33 : nb3) * 128;
  const int tid = threadIdx.x;
  const int lane = tid & 63, l16 = lane & 15, quad = lane >> 4;
  const int wv = tid >> 6, wr = wv >> 1, wc = wv & 1;
  const int sr = tid >> 2, sc = (tid & 3) * 16;

  v4f acc[4][4];
  const v4f z4 = {0.f, 0.f, 0.f, 0.f};
  for (int i = 0; i < 4; ++i)
    for (int n = 0; n < 4; ++n) acc[i][n] = z4;

  for (int k0 = 0; k0 < kC; k0 += 64) {
    // stage A: tokens (non-vmode) or weight-transpose (vmode)
    if (!vmode) {
      const int t = m0 + sr;  // rows m0..m0+63; second half below
      for (int p = 0; p < 2; ++p) {
        const int r = p * 64 + sr;
        const int tt = m0 + r;
        v8s v0 = {0, 0, 0, 0, 0, 0, 0, 0}, v1 = v0;
        if (tt < kRows) {
          const int bb = tt / kN1, mm = tt - bb * kN1;
          const float* s = x + ((size_t)(bb * 1026 + xoff + mm)) * kC + k0 + sc;
          const float4 f0 = *(const float4*)s;
          const float4 f1 = *(const float4*)(s + 4);
          const float4 f2 = *(const float4*)(s + 8);
          const float4 f3 = *(const float4*)(s + 12);
          v0 = (v8s){(short)f2b(f0.x), (short)f2b(f0.y), (short)f2b(f0.z),
                     (short)f2b(f0.w), (short)f2b(f1.x), (short)f2b(f1.y),
                     (short)f2b(f1.z), (short)f2b(f1.w)};
          v1 = (v8s){(short)f2b(f2.x), (short)f2b(f2.y), (short)f2b(f2.z),
                     (short)f2b(f2.w), (short)f2b(f3.x), (short)f2b(f3.y),
                     (short)f2b(f3.z), (short)f2b(f3.w)};
        }
        *(v8s*)&As[r][sc] = v0;
        *(v8s*)&As[r][sc + 8] = v1;
      }
      (void)t;
    } else {
      stage_wt(As, Wn, k0, m0, tid);
    }
    // stage B: weight-transpose (non-vmode) or tokens (vmode)
    if (!vmode) {
      stage_wt(Bs, Wn, k0, n0, tid);
    } else {
      for (int p = 0; p < 2; ++p) {
        const int r = p * 64 + sr;
        const int tt = n0 + r;
        v8s v0 = {0, 0, 0, 0, 0, 0, 0, 0}, v1 = v0;
        if (tt < kRows) {
          const int bb = tt / kN1, mm = tt - bb * kN1;
          const float* s = x + ((size_t)(bb * 1026 + xoff + mm)) * kC + k0 + sc;
          const float4 f0 = *(const float4*)s;
          const float4 f1 = *(const float4*)(s + 4);
          const float4 f2 = *(const float4*)(s + 8);
          const float4 f3 = *(const float4*)(s + 12);
          v0 = (v8s){(short)f2b(f0.x), (short)f2b(f0.y), (short)f2b(f0.z),
                     (short)f2b(f0.w), (short)f2b(f1.x), (short)f2b(f1.y),
                     (short)f2b(f1.z), (short)f2b(f1.w)};
          v1 = (v8s){(short)f2b(f2.x), (short)f2b(f2.y), (short)f2b(f2.z),
                     (short)f2b(f2.w), (short)f2b(f3.x), (short)f2b(f3.y),
                     (short)f2b(f3.z), (short)f2b(f3.w)};
        }
        *(v8s*)&Bs[r][sc] = v0;
        *(v8s*)&Bs[r][sc + 8] = v1;
      }
    }
    __syncthreads();
    for (int ks = 0; ks < 2; ++ks) {
      v8s af[4], bfr[4];
      for (int i = 0; i < 4; ++i)
        af[i] = *(const v8s*)&As[wr * 64 + i * 16 + l16][ks * 32 + quad * 8];
      for (int n = 0; n < 4; ++n)
        bfr[n] = *(const v8s*)&Bs[wc * 64 + n * 16 + l16][ks * 32 + quad * 8];
      for (int i = 0; i < 4; ++i)
        for (int n = 0; n < 4; ++n)
          acc[i][n] = __builtin_amdgcn_mfma_f32_16x16x32_bf16(af[i], bfr[n],
                                                              acc[i][n], 0, 0, 0);
    }
    __syncthreads();
  }

  if (!vmode) {
    u16* outp = (op == 0) ? Qb : Kb;
    const float osc = (op == 0) ? 0.125f : 1.0f;
    float bv4[4];
    for (int nt = 0; nt < 4; ++nt) bv4[nt] = bias[n0 + wc * 64 + nt * 16 + l16];
    for (int i = 0; i < 4; ++i) {
      const int rowb = m0 + wr * 64 + i * 16 + quad * 4;
      for (int r = 0; r < 4; ++r) {
        const int row = rowb + r;
        if (row >= kRows) continue;
        for (int nt = 0; nt < 4; ++nt) {
          const int col = n0 + wc * 64 + nt * 16 + l16;
          outp[(size_t)row * kC + col] = f2b((acc[i][nt][r] + bv4[nt]) * osc);
        }
      }
    }
  } else {
    u16* Vt = (op == 2) ? Vt1 : Vt2;
    for (int nt = 0; nt < 4; ++nt) {
      const int t = n0 + wc * 64 + nt * 16 + l16;  // token
      if (t >= kRows) continue;
      const int bb = t / kN1, mm = t - bb * kN1;
      for (int i = 0; i < 4; ++i) {
        const int colb = m0 + wr * 64 + i * 16 + quad * 4;
        for (int r = 0; r < 4; ++r) {
          const int col = colb + r;
          const int hh = col >> 6, d = col & 63;
          Vt[((size_t)(bb * kH + hh) * 64 + d) * kPld + mm] =
              f2b(acc[i][nt][r] + bias[col]);
        }
      }
    }
  }
}

// ---- fused flash attention: O-step split by output columns per wave,
//      Q-frags in regs, register-prefetched K/V, no-max softmax, XCD swizzle.
__global__ __launch_bounds__(256) void attn_fused(const u16* __restrict__ Qb,
                                                  const u16* __restrict__ Kb,
                                                  const u16* __restrict__ Vt1,
                                                  const u16* __restrict__ Vt2,
                                                  u16* __restrict__ PRE) {
  __shared__ __align__(16) u16 Ks[64][72];
  __shared__ __align__(16) u16 Vs[128][72];
  __shared__ __align__(16) u16 Ps[64][72];
  __shared__ float lsumS[64];
  const int bid = blockIdx.x;
  const int xcd = bid & 7;
  const int t6 = bid >> 3;           // 0..53
  const int bh = xcd * 6 + (t6 % 6); // 0..47
  const int q0 = (t6 / 6) * 64;      // 9 q-tiles
  const int b = bh / kH, hh = bh - b * kH;
  const int tid = threadIdx.x;
  const int w = tid >> 6, lane = tid & 63, l16 = lane & 15, quad = lane >> 4;
  v8s aq0, aq1;
  {  // Q fragments straight from global (each wave reads only its 16 rows)
    int qr = q0 + w * 16 + l16;
    if (qr > 512) qr = 512;  // clamp: dup row, results discarded at write
    const u16* qs = Qb + ((size_t)(b * kN1 + qr)) * kC + hh * 64 + quad * 8;
    aq0 = *(const v8s*)qs;
    aq1 = *(const v8s*)(qs + 32);
  }
  const int ksr = tid >> 2, ksc = (tid & 3) * 16;
  const int vd = tid >> 1, vc = (tid & 1) * 32;
  const u16* kbase = Kb + (size_t)b * kN1 * kC + hh * 64 + ksc;
  const u16* vbase = ((vd < 64) ? (Vt1 + ((size_t)bh * 64 + vd) * kPld)
                                : (Vt2 + ((size_t)bh * 64 + (vd - 64)) * kPld)) +
                     vc;
  v8s kr0, kr1, vr0, vr1, vr2, vr3;
  {  // prefetch kt=0
    const u16* s = kbase + (size_t)ksr * kC;
    kr0 = *(const v8s*)s;
    kr1 = *(const v8s*)(s + 8);
    vr0 = *(const v8s*)(vbase);
    vr1 = *(const v8s*)(vbase + 8);
    vr2 = *(const v8s*)(vbase + 16);
    vr3 = *(const v8s*)(vbase + 24);
  }
  float lsum[4] = {0.f, 0.f, 0.f, 0.f};
  v4f Oacc[4][2];  // [m-frag][n-frag]: 64 q x 32 cols per wave
  const v4f z4 = {0.f, 0.f, 0.f, 0.f};
  for (int mi = 0; mi < 4; ++mi)
    for (int ni = 0; ni < 2; ++ni) Oacc[mi][ni] = z4;

  for (int kt = 0; kt < 9; ++kt) {
    const int k0 = kt * 64;
    __syncthreads();  // prior iter's Ks/Vs/Ps reads complete
    *(v8s*)&Ks[ksr][ksc] = kr0;
    *(v8s*)&Ks[ksr][ksc + 8] = kr1;
    *(v8s*)&Vs[vd][vc] = vr0;
    *(v8s*)&Vs[vd][vc + 8] = vr1;
    *(v8s*)&Vs[vd][vc + 16] = vr2;
    *(v8s*)&Vs[vd][vc + 24] = vr3;
    __syncthreads();
    if (kt < 8) {  // register prefetch of kt+1, hidden under compute
      int ki = k0 + 64 + ksr;
      if (ki > 512) ki = 512;  // masked in exp; avoids OOB
      const u16* s = kbase + (size_t)ki * kC;
      kr0 = *(const v8s*)s;
      kr1 = *(const v8s*)(s + 8);
      const u16* t = vbase + k0 + 64;  // pad cols finite poison, P=0 kills them
      vr0 = *(const v8s*)t;
      vr1 = *(const v8s*)(t + 8);
      vr2 = *(const v8s*)(t + 16);
      vr3 = *(const v8s*)(t + 24);
    }
    // S-tile: wave w owns q rows w*16..+15, cols k0..k0+63
    v4f sacc[4];
    for (int nt = 0; nt < 4; ++nt) sacc[nt] = z4;
    for (int nt = 0; nt < 4; ++nt) {
      const v8s bk0 = *(const v8s*)&Ks[nt * 16 + l16][quad * 8];
      sacc[nt] = __builtin_amdgcn_mfma_f32_16x16x32_bf16(aq0, bk0, sacc[nt], 0, 0, 0);
      const v8s bk1 = *(const v8s*)&Ks[nt * 16 + l16][32 + quad * 8];
      sacc[nt] = __builtin_amdgcn_mfma_f32_16x16x32_bf16(aq1, bk1, sacc[nt], 0, 0, 0);
    }
    // P = exp(S); mask only needed on the last tile (cols 513..575)
    if (kt < 8) {
      for (int r = 0; r < 4; ++r) {
        float ps = 0.f;
        for (int nt = 0; nt < 4; ++nt) {
          const float p = __expf(sacc[nt][r]);
          ps += p;
          Ps[w * 16 + quad * 4 + r][nt * 16 + l16] = f2b(p);
        }
        lsum[r] += ps;
      }
    } else {
      for (int r = 0; r < 4; ++r) {
        float ps = 0.f;
        for (int nt = 0; nt < 4; ++nt) {
          const float p =
              (nt == 0 && l16 == 0) ? __expf(sacc[nt][r]) : 0.f;  // col 512
          ps += p;
          Ps[w * 16 + quad * 4 + r][nt * 16 + l16] = f2b(p);
        }
        lsum[r] += ps;
      }
    }
    __syncthreads();  // Ps visible to all waves
    // O += P @ V: wave w covers cols [w*32, w*32+32), all 64 q rows
    for (int kc = 0; kc < 2; ++kc) {
      v8s bv[2];
      for (int ni = 0; ni < 2; ++ni)
        bv[ni] = *(const v8s*)&Vs[w * 32 + ni * 16 + l16][kc * 32 + quad * 8];
      for (int mi = 0; mi < 4; ++mi) {
        const v8s ap = *(const v8s*)&Ps[mi * 16 + l16][kc * 32 + quad * 8];
        for (int ni = 0; ni < 2; ++ni)
          Oacc[mi][ni] = __builtin_amdgcn_mfma_f32_16x16x32_bf16(
              ap, bv[ni], Oacc[mi][ni], 0, 0, 0);
      }
    }
  }
  // publish per-row softmax sums (each wave owns rows w*16..+15)
  for (int r = 0; r < 4; ++r) {
    float s = lsum[r];
    for (int o = 1; o <= 8; o <<= 1) s += __shfl_xor(s, o);
    if (l16 == 0) lsumS[w * 16 + quad * 4 + r] = s;
  }
  __syncthreads();
  // epilogue: wave w writes cols [w*32, w*32+32)
  const int colb = hh * 64 + ((w * 32) & 63);
  const int rbase = b * 1026 + ((w < 2) ? 0 : kN1);
  for (int mi = 0; mi < 4; ++mi) {
    for (int r = 0; r < 4; ++r) {
      const int q = q0 + mi * 16 + quad * 4 + r;
      if (q >= kN1) continue;
      const float rinv = 1.f / lsumS[mi * 16 + quad * 4 + r];
      for (int ni = 0; ni < 2; ++ni) {
        const int col = colb + ni * 16 + l16;
        PRE[(size_t)(rbase + q) * kC + col] = f2b(Oacc[mi][ni][r] * rinv);
      }
    }
  }
}

// ---- OUT = PRE @ Wo + bo (fp32 out); Wo transposed inline during staging ----
__global__ __launch_bounds__(256) void out_mfma(const u16* __restrict__ PRE,
                                                const float* __restrict__ Wo,
                                                const float* __restrict__ bo,
                                                float* __restrict__ OUT) {
  __shared__ __align__(16) u16 As[128][72];
  __shared__ __align__(16) u16 Bs[128][72];
  const int m0 = blockIdx.x * 128, n0 = blockIdx.y * 128;
  const int tid = threadIdx.x;
  const int lane = tid & 63, l16 = lane & 15, quad = lane >> 4;
  const int wv = tid >> 6, wr = wv >> 1, wc = wv & 1;
  const int sr = tid >> 2, sc = (tid & 3) * 16;
  v4f acc[4][4];
  const v4f z4 = {0.f, 0.f, 0.f, 0.f};
  for (int i = 0; i < 4; ++i)
    for (int n = 0; n < 4; ++n) acc[i][n] = z4;
  for (int k0 = 0; k0 < kC; k0 += 64) {
    for (int p = 0; p < 2; ++p) {
      const int r = p * 64 + sr;
      v8s v0 = {0, 0, 0, 0, 0, 0, 0, 0}, v1 = v0;
      const int row = m0 + r;
      if (row < kRows2) {
        const u16* s = PRE + (size_t)row * kC + k0 + sc;
        v0 = *(const v8s*)s;
        v1 = *(const v8s*)(s + 8);
      }
      *(v8s*)&As[r][sc] = v0;
      *(v8s*)&As[r][sc + 8] = v1;
    }
    stage_wt(Bs, Wo, k0, n0, tid);
    __syncthreads();
    for (int ks = 0; ks < 2; ++ks) {
      v8s af[4], bfr[4];
      for (int i = 0; i < 4; ++i)
        af[i] = *(const v8s*)&As[wr * 64 + i * 16 + l16][ks * 32 + quad * 8];
      for (int n = 0; n < 4; ++n)
        bfr[n] = *(const v8s*)&Bs[wc * 64 + n * 16 + l16][ks * 32 + quad * 8];
      for (int i = 0; i < 4; ++i)
        for (int n = 0; n < 4; ++n)
          acc[i][n] = __builtin_amdgcn_mfma_f32_16x16x32_bf16(af[i], bfr[n],
                                                              acc[i][n], 0, 0, 0);
    }
    __syncthreads();
  }
  float bv4[4];
  for (int nt = 0; nt < 4; ++nt) bv4[nt] = bo[n0 + wc * 64 + nt * 16 + l16];
  for (int i = 0; i < 4; ++i) {
    const int rowb = m0 + wr * 64 + i * 16 + quad * 4;
    for (int r = 0; r < 4; ++r) {
      const int row = rowb + r;
      if (row >= kRows2) continue;
      for (int nt = 0; nt < 4; ++nt) {
        const int col = n0 + wc * 64 + nt * 16 + l16;
        OUT[(size_t)row * kC + col] = acc[i][nt][r] + bv4[nt];
      }
    }
  }
}

extern "C" void kernel_launch(void* const* d_in, const int* in_sizes, int n_in,
                              void* d_out, int out_size, void* d_ws,
                              size_t ws_size, hipStream_t stream) {
  const float* x = (const float*)d_in[0];
  const float* Wq1 = (const float*)d_in[1];
  const float* bq1 = (const float*)d_in[2];
  const float* Wq2 = (const float*)d_in[3];
  const float* bq2 = (const float*)d_in[4];
  const float* Wk1 = (const float*)d_in[5];
  const float* bk1 = (const float*)d_in[6];
  const float* Wk2 = (const float*)d_in[7];
  const float* bk2 = (const float*)d_in[8];
  const float* Wv1 = (const float*)d_in[9];
  const float* bv1 = (const float*)d_in[10];
  const float* Wv2 = (const float*)d_in[11];
  const float* bv2 = (const float*)d_in[12];
  const float* Wo = (const float*)d_in[13];
  const float* bo = (const float*)d_in[14];
  const float* wts = (const float*)d_in[15];
  const float* gum = (const float*)d_in[16];

  u16* Qb = (u16*)d_ws;                          // 4104*384
  u16* Kb = Qb + (size_t)kRows * kC;             // 4104*384
  u16* Vt1 = Kb + (size_t)kRows * kC;            // 48*64*576
  u16* Vt2 = Vt1 + (size_t)kBH * 64 * kPld;      // 48*64*576
  u16* PRE = Vt2 + (size_t)kBH * 64 * kPld;      // 8208*384
  // total ~16.5 MB of d_ws

  qkv_mfma<<<dim3(400), 256, 0, stream>>>(
      x, Wq1, Wq2, Wk1, Wk2, Wv1, Wv2, bq1, bq2, bk1, bk2, bv1, bv2, wts, gum,
      Qb, Kb, Vt1, Vt2);
  attn_fused<<<dim3(432), 256, 0, stream>>>(Qb, Kb, Vt1, Vt2, PRE);
  out_mfma<<<dim3(65, 3), 256, 0, stream>>>(PRE, Wo, bo, (float*)d_out);
}

// Round 10
// 147.531 us; speedup vs baseline: 1.0575x; 1.0575x over previous
//
#include <hip/hip_runtime.h>

typedef unsigned short u16;
typedef short v8s __attribute__((ext_vector_type(8)));
typedef float v4f __attribute__((ext_vector_type(4)));

namespace {
constexpr int kC = 384;
constexpr int kN1 = 513;
constexpr int kH = 6;
constexpr int kBH = 48;      // B*H
constexpr int kRows = 4104;  // B*N1 tokens per half
constexpr int kRows2 = 8208; // B*M
constexpr int kPld = 576;    // Vt k-stride in bf16 elems (64*9)
}  // namespace

__device__ __forceinline__ u16 f2b(float f) {
  unsigned int u = __float_as_uint(f);
  u += 0x7fffu + ((u >> 16) & 1u);
  return (u16)(u >> 16);
}

__device__ __forceinline__ int gumbel_argmax(const float* __restrict__ w,
                                             const float* __restrict__ g) {
  float v0 = w[0] + g[0], v1 = w[1] + g[1], v2 = w[2] + g[2], v3 = w[3] + g[3];
  int j = 0;
  float m = v0;
  if (v1 > m) { m = v1; j = 1; }
  if (v2 > m) { m = v2; j = 2; }
  if (v3 > m) { m = v3; j = 3; }
  return j;
}

// ---- weights-only prep: select + transpose + convert 5 weights to bf16 [n][k]
// (dedicated coalesced pass beats inline per-block transpose — R9 measured +8us)
__global__ __launch_bounds__(256) void prep_w(
    const float* __restrict__ Wq1, const float* __restrict__ Wq2,
    const float* __restrict__ Wk1, const float* __restrict__ Wk2,
    const float* __restrict__ Wv1, const float* __restrict__ Wv2,
    const float* __restrict__ Wo, const float* __restrict__ wts,
    const float* __restrict__ gum, u16* __restrict__ Wqt,
    u16* __restrict__ Wkt, u16* __restrict__ Wv1t, u16* __restrict__ Wv2t,
    u16* __restrict__ Wot) {
  __shared__ float tb[32][33];
  const int bx = blockIdx.x;
  const int z = bx / 144, rem = bx - z * 144;
  const int c0 = (rem % 12) * 32, r0 = (rem / 12) * 32;
  const int j = gumbel_argmax(wts, gum);
  const float* src;
  u16* dst;
  switch (z) {
    case 0: src = (j < 2) ? Wq1 : Wq2; dst = Wqt; break;
    case 1: src = (j == 0 || j == 2) ? Wk1 : Wk2; dst = Wkt; break;
    case 2: src = Wv1; dst = Wv1t; break;
    case 3: src = Wv2; dst = Wv2t; break;
    default: src = Wo; dst = Wot; break;
  }
  const int tx = threadIdx.x & 31, ty = threadIdx.x >> 5;
  for (int p = 0; p < 4; ++p)
    tb[ty + p * 8][tx] = src[(size_t)(r0 + ty + p * 8) * kC + c0 + tx];
  __syncthreads();
  for (int p = 0; p < 4; ++p)
    dst[(size_t)(c0 + ty + p * 8) * kC + r0 + tx] = f2b(tb[tx][ty + p * 8]);
}

// ---- fused QKV projections, bf16 MFMA; x converted fp32->bf16 inline ----
// 1-D grid of 400: xcd=bid&7 pairs to op=xcd>>1 (weights L2-resident per XCD
// pair). op0: Q = 0.125*(xsel @ Wq + bq); op1: K; op2/3: Vt (transposed out).
__global__ __launch_bounds__(256) void qkv_mfma(
    const float* __restrict__ x, const u16* __restrict__ Wqt,
    const u16* __restrict__ Wkt, const u16* __restrict__ Wv1t,
    const u16* __restrict__ Wv2t, const float* __restrict__ bq1,
    const float* __restrict__ bq2, const float* __restrict__ bk1,
    const float* __restrict__ bk2, const float* __restrict__ bv1,
    const float* __restrict__ bv2, const float* __restrict__ wts,
    const float* __restrict__ gum, u16* __restrict__ Qb, u16* __restrict__ Kb,
    u16* __restrict__ Vt1, u16* __restrict__ Vt2) {
  const int bid = blockIdx.x;
  const int xcd = bid & 7;
  const int op = xcd >> 1;
  const int wu = (bid >> 3) * 2 + (xcd & 1);
  if (wu >= 99) return;
  const int mb33 = wu / 3, nb3 = wu - mb33 * 3;

  __shared__ __align__(16) u16 As[128][72];
  __shared__ __align__(16) u16 Bs[128][72];
  const int j = gumbel_argmax(wts, gum);
  const bool vmode = (op >= 2);
  const float* bias;
  int xoff;
  const u16* Wt;
  if (op == 0) {
    bias = (j < 2) ? bq1 : bq2; xoff = (j < 2) ? 0 : kN1; Wt = Wqt;
  } else if (op == 1) {
    const bool u1 = (j == 0 || j == 2);
    bias = u1 ? bk1 : bk2; xoff = u1 ? 0 : kN1; Wt = Wkt;
  } else if (op == 2) {
    bias = bv1; xoff = 0; Wt = Wv1t;
  } else {
    bias = bv2; xoff = kN1; Wt = Wv2t;
  }
  const int m0 = (vmode ? nb3 : mb33) * 128;
  const int n0 = (vmode ? mb33 : nb3) * 128;
  const int tid = threadIdx.x;
  const int lane = tid & 63, l16 = lane & 15, quad = lane >> 4;
  const int wv = tid >> 6, wr = wv >> 1, wc = wv & 1;
  const int sr = tid >> 2, sc = (tid & 3) * 16;

  v4f acc[4][4];
  const v4f z4 = {0.f, 0.f, 0.f, 0.f};
  for (int i = 0; i < 4; ++i)
    for (int n = 0; n < 4; ++n) acc[i][n] = z4;

  for (int k0 = 0; k0 < kC; k0 += 64) {
    for (int p = 0; p < 2; ++p) {  // stage A (M operand)
      const int r = p * 64 + sr;
      v8s v0 = {0, 0, 0, 0, 0, 0, 0, 0}, v1 = v0;
      if (!vmode) {
        const int t = m0 + r;
        if (t < kRows) {
          const int bb = t / kN1, mm = t - bb * kN1;
          const float* s = x + ((size_t)(bb * 1026 + xoff + mm)) * kC + k0 + sc;
          const float4 f0 = *(const float4*)s;
          const float4 f1 = *(const float4*)(s + 4);
          const float4 f2 = *(const float4*)(s + 8);
          const float4 f3 = *(const float4*)(s + 12);
          v0 = (v8s){(short)f2b(f0.x), (short)f2b(f0.y), (short)f2b(f0.z),
                     (short)f2b(f0.w), (short)f2b(f1.x), (short)f2b(f1.y),
                     (short)f2b(f1.z), (short)f2b(f1.w)};
          v1 = (v8s){(short)f2b(f2.x), (short)f2b(f2.y), (short)f2b(f2.z),
                     (short)f2b(f2.w), (short)f2b(f3.x), (short)f2b(f3.y),
                     (short)f2b(f3.z), (short)f2b(f3.w)};
        }
      } else {
        const u16* s = Wt + (size_t)(m0 + r) * kC + k0 + sc;
        v0 = *(const v8s*)s;
        v1 = *(const v8s*)(s + 8);
      }
      *(v8s*)&As[r][sc] = v0;
      *(v8s*)&As[r][sc + 8] = v1;
    }
    for (int p = 0; p < 2; ++p) {  // stage B (N operand)
      const int r = p * 64 + sr;
      v8s v0 = {0, 0, 0, 0, 0, 0, 0, 0}, v1 = v0;
      if (!vmode) {
        const u16* s = Wt + (size_t)(n0 + r) * kC + k0 + sc;
        v0 = *(const v8s*)s;
        v1 = *(const v8s*)(s + 8);
      } else {
        const int t = n0 + r;
        if (t < kRows) {
          const int bb = t / kN1, mm = t - bb * kN1;
          const float* s = x + ((size_t)(bb * 1026 + xoff + mm)) * kC + k0 + sc;
          const float4 f0 = *(const float4*)s;
          const float4 f1 = *(const float4*)(s + 4);
          const float4 f2 = *(const float4*)(s + 8);
          const float4 f3 = *(const float4*)(s + 12);
          v0 = (v8s){(short)f2b(f0.x), (short)f2b(f0.y), (short)f2b(f0.z),
                     (short)f2b(f0.w), (short)f2b(f1.x), (short)f2b(f1.y),
                     (short)f2b(f1.z), (short)f2b(f1.w)};
          v1 = (v8s){(short)f2b(f2.x), (short)f2b(f2.y), (short)f2b(f2.z),
                     (short)f2b(f2.w), (short)f2b(f3.x), (short)f2b(f3.y),
                     (short)f2b(f3.z), (short)f2b(f3.w)};
        }
      }
      *(v8s*)&Bs[r][sc] = v0;
      *(v8s*)&Bs[r][sc + 8] = v1;
    }
    __syncthreads();
    for (int ks = 0; ks < 2; ++ks) {
      v8s af[4], bfr[4];
      for (int i = 0; i < 4; ++i)
        af[i] = *(const v8s*)&As[wr * 64 + i * 16 + l16][ks * 32 + quad * 8];
      for (int n = 0; n < 4; ++n)
        bfr[n] = *(const v8s*)&Bs[wc * 64 + n * 16 + l16][ks * 32 + quad * 8];
      for (int i = 0; i < 4; ++i)
        for (int n = 0; n < 4; ++n)
          acc[i][n] = __builtin_amdgcn_mfma_f32_16x16x32_bf16(af[i], bfr[n],
                                                              acc[i][n], 0, 0, 0);
    }
    __syncthreads();
  }

  if (!vmode) {
    u16* outp = (op == 0) ? Qb : Kb;
    const float osc = (op == 0) ? 0.125f : 1.0f;
    float bv4[4];
    for (int nt = 0; nt < 4; ++nt) bv4[nt] = bias[n0 + wc * 64 + nt * 16 + l16];
    for (int i = 0; i < 4; ++i) {
      const int rowb = m0 + wr * 64 + i * 16 + quad * 4;
      for (int r = 0; r < 4; ++r) {
        const int row = rowb + r;
        if (row >= kRows) continue;
        for (int nt = 0; nt < 4; ++nt) {
          const int col = n0 + wc * 64 + nt * 16 + l16;
          outp[(size_t)row * kC + col] = f2b((acc[i][nt][r] + bv4[nt]) * osc);
        }
      }
    }
  } else {
    u16* Vt = (op == 2) ? Vt1 : Vt2;
    for (int nt = 0; nt < 4; ++nt) {
      const int t = n0 + wc * 64 + nt * 16 + l16;  // token
      if (t >= kRows) continue;
      const int bb = t / kN1, mm = t - bb * kN1;
      for (int i = 0; i < 4; ++i) {
        const int colb = m0 + wr * 64 + i * 16 + quad * 4;
        for (int r = 0; r < 4; ++r) {
          const int col = colb + r;
          const int hh = col >> 6, d = col & 63;
          Vt[((size_t)(bb * kH + hh) * 64 + d) * kPld + mm] =
              f2b(acc[i][nt][r] + bias[col]);
        }
      }
    }
  }
}

// ---- fused flash attention: Q-frags in registers, register-prefetched K/V,
//      no-max softmax. 1-D grid 432: xcd=bid&7, bh=xcd*6+(bid>>3)%6 so all 9
//      q-tiles of a head hit one XCD's L2 (6 heads = 3.8 MB < 4 MB L2).
__global__ __launch_bounds__(256) void attn_fused(const u16* __restrict__ Qb,
                                                  const u16* __restrict__ Kb,
                                                  const u16* __restrict__ Vt1,
                                                  const u16* __restrict__ Vt2,
                                                  u16* __restrict__ PRE) {
  __shared__ __align__(16) u16 Ks[64][72];
  __shared__ __align__(16) u16 Vs[128][72];
  __shared__ __align__(16) u16 Ps[4][16][72];
  const int bid = blockIdx.x;
  const int xcd = bid & 7;
  const int t6 = bid >> 3;           // 0..53
  const int bh = xcd * 6 + (t6 % 6); // 0..47
  const int q0 = (t6 / 6) * 64;      // 9 q-tiles
  const int b = bh / kH, hh = bh - b * kH;
  const int tid = threadIdx.x;
  const int w = tid >> 6, lane = tid & 63, l16 = lane & 15, quad = lane >> 4;
  v8s aq0, aq1;
  {  // Q fragments straight from global (each wave reads only its 16 rows)
    int qr = q0 + w * 16 + l16;
    if (qr > 512) qr = 512;  // clamp: dup row, results discarded at write
    const u16* qs = Qb + ((size_t)(b * kN1 + qr)) * kC + hh * 64 + quad * 8;
    aq0 = *(const v8s*)qs;
    aq1 = *(const v8s*)(qs + 32);
  }
  const int ksr = tid >> 2, ksc = (tid & 3) * 16;
  const int vd = tid >> 1, vc = (tid & 1) * 32;
  const u16* kbase = Kb + (size_t)b * kN1 * kC + hh * 64 + ksc;
  const u16* vbase = ((vd < 64) ? (Vt1 + ((size_t)bh * 64 + vd) * kPld)
                                : (Vt2 + ((size_t)bh * 64 + (vd - 64)) * kPld)) +
                     vc;
  v8s kr0, kr1, vr0, vr1, vr2, vr3;
  {  // prefetch kt=0
    const u16* s = kbase + (size_t)ksr * kC;
    kr0 = *(const v8s*)s;
    kr1 = *(const v8s*)(s + 8);
    vr0 = *(const v8s*)(vbase);
    vr1 = *(const v8s*)(vbase + 8);
    vr2 = *(const v8s*)(vbase + 16);
    vr3 = *(const v8s*)(vbase + 24);
  }
  float lsum[4] = {0.f, 0.f, 0.f, 0.f};
  v4f Oacc[8];
  const v4f z4 = {0.f, 0.f, 0.f, 0.f};
  for (int n = 0; n < 8; ++n) Oacc[n] = z4;

  for (int kt = 0; kt < 9; ++kt) {
    const int k0 = kt * 64;
    __syncthreads();  // prior iter's LDS reads complete
    *(v8s*)&Ks[ksr][ksc] = kr0;
    *(v8s*)&Ks[ksr][ksc + 8] = kr1;
    *(v8s*)&Vs[vd][vc] = vr0;
    *(v8s*)&Vs[vd][vc + 8] = vr1;
    *(v8s*)&Vs[vd][vc + 16] = vr2;
    *(v8s*)&Vs[vd][vc + 24] = vr3;
    __syncthreads();
    if (kt < 8) {  // register prefetch of kt+1, hidden under compute
      int ki = k0 + 64 + ksr;
      if (ki > 512) ki = 512;  // masked in exp; avoids OOB
      const u16* s = kbase + (size_t)ki * kC;
      kr0 = *(const v8s*)s;
      kr1 = *(const v8s*)(s + 8);
      const u16* t = vbase + k0 + 64;  // pad cols finite poison, P=0 kills them
      vr0 = *(const v8s*)t;
      vr1 = *(const v8s*)(t + 8);
      vr2 = *(const v8s*)(t + 16);
      vr3 = *(const v8s*)(t + 24);
    }
    v4f sacc[4];
    for (int nt = 0; nt < 4; ++nt) sacc[nt] = z4;
    for (int nt = 0; nt < 4; ++nt) {
      const v8s bk0 = *(const v8s*)&Ks[nt * 16 + l16][quad * 8];
      sacc[nt] = __builtin_amdgcn_mfma_f32_16x16x32_bf16(aq0, bk0, sacc[nt], 0, 0, 0);
      const v8s bk1 = *(const v8s*)&Ks[nt * 16 + l16][32 + quad * 8];
      sacc[nt] = __builtin_amdgcn_mfma_f32_16x16x32_bf16(aq1, bk1, sacc[nt], 0, 0, 0);
    }
    for (int r = 0; r < 4; ++r) {
      float ps = 0.f;
      for (int nt = 0; nt < 4; ++nt) {
        const int col = k0 + nt * 16 + l16;
        const float p = (col < kN1) ? __expf(sacc[nt][r]) : 0.f;
        ps += p;
        Ps[w][quad * 4 + r][nt * 16 + l16] = f2b(p);
      }
      lsum[r] += ps;
    }
    for (int kc = 0; kc < 2; ++kc) {
      const v8s ap = *(const v8s*)&Ps[w][l16][kc * 32 + quad * 8];
      for (int n = 0; n < 8; ++n) {
        const v8s bv = *(const v8s*)&Vs[n * 16 + l16][kc * 32 + quad * 8];
        Oacc[n] = __builtin_amdgcn_mfma_f32_16x16x32_bf16(ap, bv, Oacc[n], 0, 0, 0);
      }
    }
  }
  float rinv[4];
  for (int r = 0; r < 4; ++r) {
    float s = lsum[r];
    for (int o = 1; o <= 8; o <<= 1) s += __shfl_xor(s, o);
    rinv[r] = 1.f / s;
  }
  for (int n = 0; n < 8; ++n) {
    const int col = hh * 64 + (n & 3) * 16 + l16;
    const int rbase = b * 1026 + ((n < 4) ? 0 : kN1);
    for (int r = 0; r < 4; ++r) {
      const int q = q0 + w * 16 + quad * 4 + r;
      if (q >= kN1) continue;
      PRE[(size_t)(rbase + q) * kC + col] = f2b(Oacc[n][r] * rinv[r]);
    }
  }
}

// ---- OUT = PRE @ Wo + bo (fp32 out) ----
__global__ __launch_bounds__(256) void out_mfma(const u16* __restrict__ PRE,
                                                const u16* __restrict__ Wot,
                                                const float* __restrict__ bo,
                                                float* __restrict__ OUT) {
  __shared__ __align__(16) u16 As[128][72];
  __shared__ __align__(16) u16 Bs[128][72];
  const int m0 = blockIdx.x * 128, n0 = blockIdx.y * 128;
  const int tid = threadIdx.x;
  const int lane = tid & 63, l16 = lane & 15, quad = lane >> 4;
  const int wv = tid >> 6, wr = wv >> 1, wc = wv & 1;
  const int sr = tid >> 2, sc = (tid & 3) * 16;
  v4f acc[4][4];
  const v4f z4 = {0.f, 0.f, 0.f, 0.f};
  for (int i = 0; i < 4; ++i)
    for (int n = 0; n < 4; ++n) acc[i][n] = z4;
  for (int k0 = 0; k0 < kC; k0 += 64) {
    for (int p = 0; p < 2; ++p) {
      const int r = p * 64 + sr;
      v8s v0 = {0, 0, 0, 0, 0, 0, 0, 0}, v1 = v0;
      const int row = m0 + r;
      if (row < kRows2) {
        const u16* s = PRE + (size_t)row * kC + k0 + sc;
        v0 = *(const v8s*)s;
        v1 = *(const v8s*)(s + 8);
      }
      *(v8s*)&As[r][sc] = v0;
      *(v8s*)&As[r][sc + 8] = v1;
      const u16* s2 = Wot + (size_t)(n0 + r) * kC + k0 + sc;
      *(v8s*)&Bs[r][sc] = *(const v8s*)s2;
      *(v8s*)&Bs[r][sc + 8] = *(const v8s*)(s2 + 8);
    }
    __syncthreads();
    for (int ks = 0; ks < 2; ++ks) {
      v8s af[4], bfr[4];
      for (int i = 0; i < 4; ++i)
        af[i] = *(const v8s*)&As[wr * 64 + i * 16 + l16][ks * 32 + quad * 8];
      for (int n = 0; n < 4; ++n)
        bfr[n] = *(const v8s*)&Bs[wc * 64 + n * 16 + l16][ks * 32 + quad * 8];
      for (int i = 0; i < 4; ++i)
        for (int n = 0; n < 4; ++n)
          acc[i][n] = __builtin_amdgcn_mfma_f32_16x16x32_bf16(af[i], bfr[n],
                                                              acc[i][n], 0, 0, 0);
    }
    __syncthreads();
  }
  float bv4[4];
  for (int nt = 0; nt < 4; ++nt) bv4[nt] = bo[n0 + wc * 64 + nt * 16 + l16];
  for (int i = 0; i < 4; ++i) {
    const int rowb = m0 + wr * 64 + i * 16 + quad * 4;
    for (int r = 0; r < 4; ++r) {
      const int row = rowb + r;
      if (row >= kRows2) continue;
      for (int nt = 0; nt < 4; ++nt) {
        const int col = n0 + wc * 64 + nt * 16 + l16;
        OUT[(size_t)row * kC + col] = acc[i][nt][r] + bv4[nt];
      }
    }
  }
}

extern "C" void kernel_launch(void* const* d_in, const int* in_sizes, int n_in,
                              void* d_out, int out_size, void* d_ws,
                              size_t ws_size, hipStream_t stream) {
  const float* x = (const float*)d_in[0];
  const float* Wq1 = (const float*)d_in[1];
  const float* bq1 = (const float*)d_in[2];
  const float* Wq2 = (const float*)d_in[3];
  const float* bq2 = (const float*)d_in[4];
  const float* Wk1 = (const float*)d_in[5];
  const float* bk1 = (const float*)d_in[6];
  const float* Wk2 = (const float*)d_in[7];
  const float* bk2 = (const float*)d_in[8];
  const float* Wv1 = (const float*)d_in[9];
  const float* bv1 = (const float*)d_in[10];
  const float* Wv2 = (const float*)d_in[11];
  const float* bv2 = (const float*)d_in[12];
  const float* Wo = (const float*)d_in[13];
  const float* bo = (const float*)d_in[14];
  const float* wts = (const float*)d_in[15];
  const float* gum = (const float*)d_in[16];

  u16* Wqt = (u16*)d_ws;                         // 147456 elems each
  u16* Wkt = Wqt + 147456;
  u16* Wv1t = Wkt + 147456;
  u16* Wv2t = Wv1t + 147456;
  u16* Wot = Wv2t + 147456;
  u16* Qb = Wot + 147456;                        // 4104*384
  u16* Kb = Qb + (size_t)kRows * kC;             // 4104*384
  u16* Vt1 = Kb + (size_t)kRows * kC;            // 48*64*576
  u16* Vt2 = Vt1 + (size_t)kBH * 64 * kPld;      // 48*64*576
  u16* PRE = Vt2 + (size_t)kBH * 64 * kPld;      // 8208*384
  // total ~18 MB of d_ws

  prep_w<<<dim3(720), 256, 0, stream>>>(Wq1, Wq2, Wk1, Wk2, Wv1, Wv2, Wo, wts,
                                        gum, Wqt, Wkt, Wv1t, Wv2t, Wot);
  qkv_mfma<<<dim3(400), 256, 0, stream>>>(
      x, Wqt, Wkt, Wv1t, Wv2t, bq1, bq2, bk1, bk2, bv1, bv2, wts, gum, Qb, Kb,
      Vt1, Vt2);
  attn_fused<<<dim3(432), 256, 0, stream>>>(Qb, Kb, Vt1, Vt2, PRE);
  out_mfma<<<dim3(65, 3), 256, 0, stream>>>(PRE, Wo ? Wot : Wot, bo,
                                            (float*)d_out);
}